// Round 1
// baseline (378.604 us; speedup 1.0000x reference)
//
#include <hip/hip_runtime.h>

typedef __attribute__((ext_vector_type(8))) short short8;
typedef __attribute__((ext_vector_type(4))) float floatx4;

#define NTYPES 64
#define CHUNK 32
#define BPT 16   // blocks per type; grid = (BPT, NTYPES)

// LDS offsets in ushort units. Row strides padded (72 / 40) so the 16-lane
// b128 fragment reads land on distinct bank quads (2-way max => free).
#define WT0_OFF 0        // 64 rows x 72   (Wt0[o][i], i<64)
#define WT1_OFF 4608     // 32 rows x 40   (Wt1[o][i], i<32)
#define WT2_OFF 5888     // 16 rows x 40   (Wt2[o][i], i<16, k16..31 zero)
#define A0_OFF  6528     // 32 rows x 72   (A0[n][i], i<64)
#define A1_OFF  8832     // 96 rows x 40   (A1[n*3+d][i], i<32)
#define A2_OFF  12672    // 160 rows x 40  (A2[n*5+d][i], i<16, k16..31 zero)
#define SMEM_USH 19072   // ~38.1 KB

__device__ __forceinline__ unsigned short f2bf(float f) {
    union { float f; unsigned u; } v; v.f = f;
    unsigned u = v.u;
    u += 0x7FFFu + ((u >> 16) & 1u);   // round-to-nearest-even
    return (unsigned short)(u >> 16);
}

// ---- pass 1: per-type counts ----
__global__ void count_kernel(const int* __restrict__ idx, int* __restrict__ ws, int n) {
    int t = blockIdx.x * blockDim.x + threadIdx.x;
    if (t < n) atomicAdd(&ws[idx[t]], 1);
}

// ---- pass 2: exclusive scan (64 entries, trivial) ----
__global__ void scan_kernel(int* ws) {
    if (threadIdx.x == 0) {
        int off = 0;
        for (int t = 0; t < NTYPES; ++t) {
            ws[64 + t]  = off;   // offsets
            ws[128 + t] = off;   // cursors
            off += ws[t];
        }
    }
}

// ---- pass 3: scatter node ids into type-sorted list ----
__global__ void scatter_kernel(const int* __restrict__ idx, int* __restrict__ ws, int n) {
    int t = blockIdx.x * blockDim.x + threadIdx.x;
    if (t < n) {
        int pos = atomicAdd(&ws[128 + idx[t]], 1);
        ws[192 + pos] = t;
    }
}

// ---- main: per-type MFMA over sorted 32-node chunks ----
__global__ __launch_bounds__(256) void main_kernel(
    const float* __restrict__ x,
    const float* __restrict__ W0,
    const float* __restrict__ W1,
    const float* __restrict__ W2,
    const int* __restrict__ ws,
    float* __restrict__ out)
{
    __shared__ __align__(16) unsigned short sm[SMEM_USH];
    __shared__ int snode[CHUNK];

    const int ty  = blockIdx.y;     // weight type this block owns
    const int tid = threadIdx.x;

    // ---- stage weights once per block: bf16, transposed [o][i] ----
    {
        const float* w = W0 + (size_t)ty * 64 * 64;   // W0[ty][i][o]
        for (int e = tid; e < 4096; e += 256) {
            int i = e >> 6, o = e & 63;
            sm[WT0_OFF + o * 72 + i] = f2bf(w[e]);
        }
        const float* w1 = W1 + (size_t)ty * 32 * 32;
        for (int e = tid; e < 1024; e += 256) {
            int i = e >> 5, o = e & 31;
            sm[WT1_OFF + o * 40 + i] = f2bf(w1[e]);
        }
        const float* w2 = W2 + (size_t)ty * 16 * 16;
        {
            int e = tid;                  // 256 threads == 256 elems
            int i = e >> 4, o = e & 15;
            sm[WT2_OFF + o * 40 + i]      = f2bf(w2[e]);
            sm[WT2_OFF + o * 40 + 16 + i] = 0;          // K-pad 16..31
        }
        for (int e = tid; e < 2560; e += 256) {          // A2 K-pad 16..31
            int row = e >> 4, k = 16 + (e & 15);
            sm[A2_OFF + row * 40 + k] = 0;
        }
    }

    const int cnt = ws[ty];
    const int off = ws[64 + ty];
    const int* list = ws + 192;

    const int wv = tid >> 6, ln = tid & 63;
    const int r = ln & 15, q4 = ln >> 4;   // frag row/col, k-quad

    for (int c = blockIdx.x; c * CHUNK < cnt; c += gridDim.x) {
        const int base = c * CHUNK;
        if (tid < CHUNK) {
            int g = base + tid;
            snode[tid] = (g < cnt) ? list[off + g] : -1;
        }
        __syncthreads();

        // ---- stage x rows -> bf16 LDS (coalesced reads, scattered b16 writes)
        for (int e = tid; e < 2048; e += 256) {          // irrep0: 32n x 64i
            int n = e >> 6, i = e & 63;
            int nd = snode[n];
            float v = (nd >= 0) ? x[(size_t)nd * 240 + i] : 0.f;
            sm[A0_OFF + n * 72 + i] = f2bf(v);
        }
        for (int e = tid; e < 3072; e += 256) {          // irrep1: 32n x (32i x 3d)
            int n = e / 96, q = e - n * 96;
            int i = q / 3, d = q - i * 3;
            int nd = snode[n];
            float v = (nd >= 0) ? x[(size_t)nd * 240 + 64 + q] : 0.f;
            sm[A1_OFF + (n * 3 + d) * 40 + i] = f2bf(v);
        }
        for (int e = tid; e < 2560; e += 256) {          // irrep2: 32n x (16i x 5d)
            int n = e / 80, q = e - n * 80;
            int i = q / 5, d = q - i * 5;
            int nd = snode[n];
            float v = (nd >= 0) ? x[(size_t)nd * 240 + 160 + q] : 0.f;
            sm[A2_OFF + (n * 5 + d) * 40 + i] = f2bf(v);
        }
        __syncthreads();

        // ---- 30 MFMA tile jobs round-robined over 4 waves ----
        for (int j = wv; j < 30; j += 4) {
            if (j < 8) {                                  // irrep0: M=32,N=64,K=64
                int mt = j >> 2, nt = j & 3;
                short8 a0 = *(const short8*)(sm + A0_OFF + (mt * 16 + r) * 72 + q4 * 8);
                short8 b0 = *(const short8*)(sm + WT0_OFF + (nt * 16 + r) * 72 + q4 * 8);
                floatx4 acc = {0.f, 0.f, 0.f, 0.f};
                acc = __builtin_amdgcn_mfma_f32_16x16x32_bf16(a0, b0, acc, 0, 0, 0);
                short8 a1 = *(const short8*)(sm + A0_OFF + (mt * 16 + r) * 72 + 32 + q4 * 8);
                short8 b1 = *(const short8*)(sm + WT0_OFF + (nt * 16 + r) * 72 + 32 + q4 * 8);
                acc = __builtin_amdgcn_mfma_f32_16x16x32_bf16(a1, b1, acc, 0, 0, 0);
#pragma unroll
                for (int rr = 0; rr < 4; ++rr) {
                    int row = mt * 16 + q4 * 4 + rr;      // node slot [0,32)
                    int nd = snode[row];
                    if (nd >= 0) out[(size_t)nd * 240 + nt * 16 + r] = acc[rr] * 0.125f;
                }
            } else if (j < 20) {                          // irrep1: M=96,N=32,K=32
                int jj = j - 8;
                int mt = jj >> 1, nt = jj & 1;
                short8 a = *(const short8*)(sm + A1_OFF + (mt * 16 + r) * 40 + q4 * 8);
                short8 b = *(const short8*)(sm + WT1_OFF + (nt * 16 + r) * 40 + q4 * 8);
                floatx4 acc = {0.f, 0.f, 0.f, 0.f};
                acc = __builtin_amdgcn_mfma_f32_16x16x32_bf16(a, b, acc, 0, 0, 0);
#pragma unroll
                for (int rr = 0; rr < 4; ++rr) {
                    int row = mt * 16 + q4 * 4 + rr;      // (n,d) flat [0,96)
                    int n = row / 3, d = row - n * 3;
                    int nd = snode[n];
                    if (nd >= 0)
                        out[(size_t)nd * 240 + 64 + (nt * 16 + r) * 3 + d] = acc[rr] * 0.17677669529663687f;
                }
            } else {                                      // irrep2: M=160,N=16,K=16(pad32)
                int mt = j - 20;
                short8 a = *(const short8*)(sm + A2_OFF + (mt * 16 + r) * 40 + q4 * 8);
                short8 b = *(const short8*)(sm + WT2_OFF + r * 40 + q4 * 8);
                floatx4 acc = {0.f, 0.f, 0.f, 0.f};
                acc = __builtin_amdgcn_mfma_f32_16x16x32_bf16(a, b, acc, 0, 0, 0);
#pragma unroll
                for (int rr = 0; rr < 4; ++rr) {
                    int row = mt * 16 + q4 * 4 + rr;      // (n,d) flat [0,160)
                    int n = row / 5, d = row - n * 5;
                    int nd = snode[n];
                    if (nd >= 0)
                        out[(size_t)nd * 240 + 160 + r * 5 + d] = acc[rr] * 0.25f;
                }
            }
        }
        __syncthreads();
    }
}

extern "C" void kernel_launch(void* const* d_in, const int* in_sizes, int n_in,
                              void* d_out, int out_size, void* d_ws, size_t ws_size,
                              hipStream_t stream) {
    const float* x  = (const float*)d_in[0];
    const float* W0 = (const float*)d_in[1];
    const float* W1 = (const float*)d_in[2];
    const float* W2 = (const float*)d_in[3];
    const int*   idx = (const int*)d_in[4];
    float* out = (float*)d_out;
    const int n = in_sizes[4];          // 65536 nodes
    int* ws = (int*)d_ws;               // [0,64)=counts [64,128)=offsets [128,192)=cursors [192,192+n)=sorted list

    hipMemsetAsync(d_ws, 0, 192 * sizeof(int), stream);
    count_kernel  <<<(n + 255) / 256, 256, 0, stream>>>(idx, ws, n);
    scan_kernel   <<<1, 64, 0, stream>>>(ws);
    scatter_kernel<<<(n + 255) / 256, 256, 0, stream>>>(idx, ws, n);
    main_kernel   <<<dim3(BPT, NTYPES), 256, 0, stream>>>(x, W0, W1, W2, ws, out);
}

// Round 2
// 181.544 us; speedup vs baseline: 2.0855x; 2.0855x over previous
//
#include <hip/hip_runtime.h>

typedef __attribute__((ext_vector_type(8))) short short8;
typedef __attribute__((ext_vector_type(4))) float floatx4;

#define NTYPES 64
#define CHUNK 32
#define BPT 16   // blocks per type; grid = (BPT, NTYPES)
#define NB  64   // histogram blocks (segments)

// ws layout (ints):
//   [0,     4096)  hist[type][block]   (type-major)
//   [4096,  8192)  exclusive scan of hist
//   [8192,  8256)  per-type counts
//   [8256,  8320)  per-type offsets
//   [8320,  8320+N) sorted node list
#define WS_HIST   0
#define WS_SCAN   4096
#define WS_CNT    8192
#define WS_OFF    8256
#define WS_LIST   8320

// LDS offsets in ushort units. Row strides padded (72 / 40) so the 16-lane
// b128 fragment reads land on distinct bank quads (2-way max => free).
#define WT0_OFF 0        // 64 rows x 72   (Wt0[o][i], i<64)
#define WT1_OFF 4608     // 32 rows x 40   (Wt1[o][i], i<32)
#define WT2_OFF 5888     // 16 rows x 40   (Wt2[o][i], i<16, k16..31 zero)
#define A0_OFF  6528     // 32 rows x 72   (A0[n][i], i<64)
#define A1_OFF  8832     // 96 rows x 40   (A1[n*3+d][i], i<32)
#define A2_OFF  12672    // 160 rows x 40  (A2[n*5+d][i], i<16, k16..31 zero)
#define SMEM_USH 19072   // ~38.1 KB

__device__ __forceinline__ unsigned short f2bf(float f) {
    union { float f; unsigned u; } v; v.f = f;
    unsigned u = v.u;
    u += 0x7FFFu + ((u >> 16) & 1u);   // round-to-nearest-even
    return (unsigned short)(u >> 16);
}

// ---- pass 1: per-segment LDS histogram -> hist[type][block] ----
__global__ __launch_bounds__(256) void hist_kernel(const int* __restrict__ idx,
                                                   int* __restrict__ ws, int n) {
    __shared__ int h[NTYPES];
    const int b = blockIdx.x, tid = threadIdx.x;
    if (tid < NTYPES) h[tid] = 0;
    __syncthreads();
    const int seg = (n + NB - 1) / NB;
    const int lo = b * seg, hi = min(lo + seg, n);
    for (int e = lo + tid; e < hi; e += 256) atomicAdd(&h[idx[e]], 1);
    __syncthreads();
    if (tid < NTYPES) ws[WS_HIST + tid * NB + b] = h[tid];
}

// ---- pass 2: exclusive scan of 4096-entry histogram (one block) ----
__global__ __launch_bounds__(256) void scan_kernel(int* __restrict__ ws, int n) {
    __shared__ int partial[256];
    const int tid = threadIdx.x;
    int v[16];
    int s = 0;
    const int base = tid * 16;
#pragma unroll
    for (int k = 0; k < 16; ++k) { v[k] = ws[WS_HIST + base + k]; s += v[k]; }
    partial[tid] = s;
    __syncthreads();
    for (int d = 1; d < 256; d <<= 1) {           // Hillis-Steele inclusive
        int t = (tid >= d) ? partial[tid - d] : 0;
        __syncthreads();
        partial[tid] += t;
        __syncthreads();
    }
    int excl = (tid == 0) ? 0 : partial[tid - 1];
#pragma unroll
    for (int k = 0; k < 16; ++k) { ws[WS_SCAN + base + k] = excl; excl += v[k]; }
    __syncthreads();
    if (tid < NTYPES) {
        int start = ws[WS_SCAN + tid * NB];
        int end   = (tid == NTYPES - 1) ? partial[255] : ws[WS_SCAN + (tid + 1) * NB];
        ws[WS_OFF + tid] = start;
        ws[WS_CNT + tid] = end - start;
    }
}

// ---- pass 3: scatter via LDS cursors (no global atomics) ----
__global__ __launch_bounds__(256) void scatter_kernel(const int* __restrict__ idx,
                                                      int* __restrict__ ws, int n) {
    __shared__ int cur[NTYPES];
    const int b = blockIdx.x, tid = threadIdx.x;
    if (tid < NTYPES) cur[tid] = ws[WS_SCAN + tid * NB + b];
    __syncthreads();
    const int seg = (n + NB - 1) / NB;
    const int lo = b * seg, hi = min(lo + seg, n);
    for (int e = lo + tid; e < hi; e += 256) {
        int pos = atomicAdd(&cur[idx[e]], 1);
        ws[WS_LIST + pos] = e;
    }
}

// ---- main: per-type MFMA over sorted 32-node chunks ----
__global__ __launch_bounds__(256) void main_kernel(
    const float* __restrict__ x,
    const float* __restrict__ W0,
    const float* __restrict__ W1,
    const float* __restrict__ W2,
    const int* __restrict__ ws,
    float* __restrict__ out)
{
    __shared__ __align__(16) unsigned short sm[SMEM_USH];
    __shared__ int snode[CHUNK];

    const int ty  = blockIdx.y;     // weight type this block owns
    const int tid = threadIdx.x;

    // ---- stage weights once per block: bf16, transposed [o][i] ----
    {
        const float* w = W0 + (size_t)ty * 64 * 64;   // W0[ty][i][o]
        for (int e = tid; e < 4096; e += 256) {
            int i = e >> 6, o = e & 63;
            sm[WT0_OFF + o * 72 + i] = f2bf(w[e]);
        }
        const float* w1 = W1 + (size_t)ty * 32 * 32;
        for (int e = tid; e < 1024; e += 256) {
            int i = e >> 5, o = e & 31;
            sm[WT1_OFF + o * 40 + i] = f2bf(w1[e]);
        }
        const float* w2 = W2 + (size_t)ty * 16 * 16;
        {
            int e = tid;                  // 256 threads == 256 elems
            int i = e >> 4, o = e & 15;
            sm[WT2_OFF + o * 40 + i]      = f2bf(w2[e]);
            sm[WT2_OFF + o * 40 + 16 + i] = 0;          // K-pad 16..31
        }
        for (int e = tid; e < 2560; e += 256) {          // A2 K-pad 16..31
            int row = e >> 4, k = 16 + (e & 15);
            sm[A2_OFF + row * 40 + k] = 0;
        }
    }

    const int cnt = ws[WS_CNT + ty];
    const int off = ws[WS_OFF + ty];
    const int* list = ws + WS_LIST;

    const int wv = tid >> 6, ln = tid & 63;
    const int r = ln & 15, q4 = ln >> 4;   // frag row/col, k-quad

    for (int c = blockIdx.x; c * CHUNK < cnt; c += gridDim.x) {
        const int base = c * CHUNK;
        if (tid < CHUNK) {
            int g = base + tid;
            snode[tid] = (g < cnt) ? list[off + g] : -1;
        }
        __syncthreads();

        // ---- stage x rows -> bf16 LDS (coalesced reads, scattered b16 writes)
        for (int e = tid; e < 2048; e += 256) {          // irrep0: 32n x 64i
            int n = e >> 6, i = e & 63;
            int nd = snode[n];
            float v = (nd >= 0) ? x[(size_t)nd * 240 + i] : 0.f;
            sm[A0_OFF + n * 72 + i] = f2bf(v);
        }
        for (int e = tid; e < 3072; e += 256) {          // irrep1: 32n x (32i x 3d)
            int n = e / 96, q = e - n * 96;
            int i = q / 3, d = q - i * 3;
            int nd = snode[n];
            float v = (nd >= 0) ? x[(size_t)nd * 240 + 64 + q] : 0.f;
            sm[A1_OFF + (n * 3 + d) * 40 + i] = f2bf(v);
        }
        for (int e = tid; e < 2560; e += 256) {          // irrep2: 32n x (16i x 5d)
            int n = e / 80, q = e - n * 80;
            int i = q / 5, d = q - i * 5;
            int nd = snode[n];
            float v = (nd >= 0) ? x[(size_t)nd * 240 + 160 + q] : 0.f;
            sm[A2_OFF + (n * 5 + d) * 40 + i] = f2bf(v);
        }
        __syncthreads();

        // ---- 30 MFMA tile jobs round-robined over 4 waves ----
        for (int j = wv; j < 30; j += 4) {
            if (j < 8) {                                  // irrep0: M=32,N=64,K=64
                int mt = j >> 2, nt = j & 3;
                short8 a0 = *(const short8*)(sm + A0_OFF + (mt * 16 + r) * 72 + q4 * 8);
                short8 b0 = *(const short8*)(sm + WT0_OFF + (nt * 16 + r) * 72 + q4 * 8);
                floatx4 acc = {0.f, 0.f, 0.f, 0.f};
                acc = __builtin_amdgcn_mfma_f32_16x16x32_bf16(a0, b0, acc, 0, 0, 0);
                short8 a1 = *(const short8*)(sm + A0_OFF + (mt * 16 + r) * 72 + 32 + q4 * 8);
                short8 b1 = *(const short8*)(sm + WT0_OFF + (nt * 16 + r) * 72 + 32 + q4 * 8);
                acc = __builtin_amdgcn_mfma_f32_16x16x32_bf16(a1, b1, acc, 0, 0, 0);
#pragma unroll
                for (int rr = 0; rr < 4; ++rr) {
                    int row = mt * 16 + q4 * 4 + rr;      // node slot [0,32)
                    int nd = snode[row];
                    if (nd >= 0) out[(size_t)nd * 240 + nt * 16 + r] = acc[rr] * 0.125f;
                }
            } else if (j < 20) {                          // irrep1: M=96,N=32,K=32
                int jj = j - 8;
                int mt = jj >> 1, nt = jj & 1;
                short8 a = *(const short8*)(sm + A1_OFF + (mt * 16 + r) * 40 + q4 * 8);
                short8 b = *(const short8*)(sm + WT1_OFF + (nt * 16 + r) * 40 + q4 * 8);
                floatx4 acc = {0.f, 0.f, 0.f, 0.f};
                acc = __builtin_amdgcn_mfma_f32_16x16x32_bf16(a, b, acc, 0, 0, 0);
#pragma unroll
                for (int rr = 0; rr < 4; ++rr) {
                    int row = mt * 16 + q4 * 4 + rr;      // (n,d) flat [0,96)
                    int n = row / 3, d = row - n * 3;
                    int nd = snode[n];
                    if (nd >= 0)
                        out[(size_t)nd * 240 + 64 + (nt * 16 + r) * 3 + d] = acc[rr] * 0.17677669529663687f;
                }
            } else {                                      // irrep2: M=160,N=16,K=16(pad32)
                int mt = j - 20;
                short8 a = *(const short8*)(sm + A2_OFF + (mt * 16 + r) * 40 + q4 * 8);
                short8 b = *(const short8*)(sm + WT2_OFF + r * 40 + q4 * 8);
                floatx4 acc = {0.f, 0.f, 0.f, 0.f};
                acc = __builtin_amdgcn_mfma_f32_16x16x32_bf16(a, b, acc, 0, 0, 0);
#pragma unroll
                for (int rr = 0; rr < 4; ++rr) {
                    int row = mt * 16 + q4 * 4 + rr;      // (n,d) flat [0,160)
                    int n = row / 5, d = row - n * 5;
                    int nd = snode[n];
                    if (nd >= 0)
                        out[(size_t)nd * 240 + 160 + r * 5 + d] = acc[rr] * 0.25f;
                }
            }
        }
        __syncthreads();
    }
}

extern "C" void kernel_launch(void* const* d_in, const int* in_sizes, int n_in,
                              void* d_out, int out_size, void* d_ws, size_t ws_size,
                              hipStream_t stream) {
    const float* x  = (const float*)d_in[0];
    const float* W0 = (const float*)d_in[1];
    const float* W1 = (const float*)d_in[2];
    const float* W2 = (const float*)d_in[3];
    const int*   idx = (const int*)d_in[4];
    float* out = (float*)d_out;
    const int n = in_sizes[4];          // 65536 nodes
    int* ws = (int*)d_ws;

    hist_kernel   <<<NB, 256, 0, stream>>>(idx, ws, n);
    scan_kernel   <<<1, 256, 0, stream>>>(ws, n);
    scatter_kernel<<<NB, 256, 0, stream>>>(idx, ws, n);
    main_kernel   <<<dim3(BPT, NTYPES), 256, 0, stream>>>(x, W0, W1, W2, ws, out);
}

// Round 3
// 163.137 us; speedup vs baseline: 2.3208x; 1.1128x over previous
//
#include <hip/hip_runtime.h>

typedef __attribute__((ext_vector_type(8))) short short8;
typedef __attribute__((ext_vector_type(4))) float floatx4;

#define NTYPES 64
#define BPT 16   // blocks per type; grid = (BPT, NTYPES); 4 waves/block => 64 wave-slots/type
#define NB  64   // histogram blocks (segments)

// ws layout (ints):
//   [0,     4096)  hist[type][block]   (type-major)
//   [4096,  8192)  exclusive scan of hist
//   [8192,  8256)  per-type counts
//   [8256,  8320)  per-type offsets
//   [8320,  8320+N) sorted node list
#define WS_HIST   0
#define WS_SCAN   4096
#define WS_CNT    8192
#define WS_OFF    8256
#define WS_LIST   8320

// LDS (ushorts): weights only, bf16, transposed [o][k], scale pre-folded.
// Row strides 72/40 keep the 16-lane b128 fragment reads <=2-way (free).
#define WT0_OFF 0        // 64 rows x 72  (k<64)
#define WT1_OFF 4608     // 32 rows x 40  (k<32)
#define WT2_OFF 5888     // 16 rows x 40  (k<16 data, k16..31 zero)
#define SMEM_USH 6528    // ~13 KB

__device__ __forceinline__ unsigned short f2bf(float f) {
    union { float f; unsigned u; } v; v.f = f;
    unsigned u = v.u;
    u += 0x7FFFu + ((u >> 16) & 1u);   // round-to-nearest-even
    return (unsigned short)(u >> 16);
}

// ---- pass 1: per-segment LDS histogram -> hist[type][block] ----
__global__ __launch_bounds__(256) void hist_kernel(const int* __restrict__ idx,
                                                   int* __restrict__ ws, int n) {
    __shared__ int h[NTYPES];
    const int b = blockIdx.x, tid = threadIdx.x;
    if (tid < NTYPES) h[tid] = 0;
    __syncthreads();
    const int seg = (n + NB - 1) / NB;
    const int lo = b * seg, hi = min(lo + seg, n);
    for (int e = lo + tid; e < hi; e += 256) atomicAdd(&h[idx[e]], 1);
    __syncthreads();
    if (tid < NTYPES) ws[WS_HIST + tid * NB + b] = h[tid];
}

// ---- pass 2: exclusive scan of 4096-entry histogram (one block) ----
__global__ __launch_bounds__(256) void scan_kernel(int* __restrict__ ws, int n) {
    __shared__ int partial[256];
    const int tid = threadIdx.x;
    int v[16];
    int s = 0;
    const int base = tid * 16;
#pragma unroll
    for (int k = 0; k < 16; ++k) { v[k] = ws[WS_HIST + base + k]; s += v[k]; }
    partial[tid] = s;
    __syncthreads();
    for (int d = 1; d < 256; d <<= 1) {
        int t = (tid >= d) ? partial[tid - d] : 0;
        __syncthreads();
        partial[tid] += t;
        __syncthreads();
    }
    int excl = (tid == 0) ? 0 : partial[tid - 1];
#pragma unroll
    for (int k = 0; k < 16; ++k) { ws[WS_SCAN + base + k] = excl; excl += v[k]; }
    __syncthreads();
    if (tid < NTYPES) {
        int start = ws[WS_SCAN + tid * NB];
        int end   = (tid == NTYPES - 1) ? partial[255] : ws[WS_SCAN + (tid + 1) * NB];
        ws[WS_OFF + tid] = start;
        ws[WS_CNT + tid] = end - start;
    }
}

// ---- pass 3: scatter via LDS cursors (no global atomics) ----
__global__ __launch_bounds__(256) void scatter_kernel(const int* __restrict__ idx,
                                                      int* __restrict__ ws, int n) {
    __shared__ int cur[NTYPES];
    const int b = blockIdx.x, tid = threadIdx.x;
    if (tid < NTYPES) cur[tid] = ws[WS_SCAN + tid * NB + b];
    __syncthreads();
    const int seg = (n + NB - 1) / NB;
    const int lo = b * seg, hi = min(lo + seg, n);
    for (int e = lo + tid; e < hi; e += 256) {
        int pos = atomicAdd(&cur[idx[e]], 1);
        ws[WS_LIST + pos] = e;
    }
}

__device__ __forceinline__ short8 pack8(const float* xv) {
    short8 a;
#pragma unroll
    for (int j = 0; j < 8; ++j) a[j] = (short)f2bf(xv[j]);
    return a;
}

// ---- main: one wave = 16 nodes; A-frags direct from global; weights in LDS;
// ---- no barriers in the node loop.
__global__ __launch_bounds__(256) void main_kernel(
    const float* __restrict__ x,
    const float* __restrict__ W0,
    const float* __restrict__ W1,
    const float* __restrict__ W2,
    const int* __restrict__ ws,
    float* __restrict__ out)
{
    __shared__ __align__(16) unsigned short sm[SMEM_USH];

    const int ty  = blockIdx.y;
    const int tid = threadIdx.x;

    // ---- stage weights once: bf16, transposed [o][k], scale folded in ----
    {
        const float* w = W0 + (size_t)ty * 64 * 64;       // [i][o]
        for (int e = tid; e < 4096; e += 256) {
            int i = e >> 6, o = e & 63;
            sm[WT0_OFF + o * 72 + i] = f2bf(w[e] * 0.125f);
        }
        const float* w1 = W1 + (size_t)ty * 32 * 32;
        for (int e = tid; e < 1024; e += 256) {
            int i = e >> 5, o = e & 31;
            sm[WT1_OFF + o * 40 + i] = f2bf(w1[e] * 0.17677669529663687f);
        }
        const float* w2 = W2 + (size_t)ty * 16 * 16;
        {
            int e = tid & 255;
            int i = e >> 4, o = e & 15;
            sm[WT2_OFF + o * 40 + i]      = f2bf(w2[e] * 0.25f);
            sm[WT2_OFF + o * 40 + 16 + i] = 0;            // K-pad 16..31
        }
    }
    __syncthreads();

    const int cnt = ws[WS_CNT + ty];
    const int off = ws[WS_OFF + ty];
    const int* list = ws + WS_LIST;

    const int wv = tid >> 6, ln = tid & 63;
    const int r = ln & 15, q4 = ln >> 4;     // frag row / k-quad
    const int slot = blockIdx.x * 4 + wv;    // wave slot within this type

    for (int base = slot * 16; base < cnt; base += BPT * 4 * 16) {
        int gi = min(base + r, cnt - 1);
        int nd = list[off + gi];             // node for A-row r (dup across q4)
        const size_t xb = (size_t)nd * 240;

        int nr[4]; bool vst[4];
#pragma unroll
        for (int rr = 0; rr < 4; ++rr) {
            int row = q4 * 4 + rr;
            nr[rr]  = __shfl(nd, row);
            vst[rr] = (base + row) < cnt;
        }

        // ================= irrep0: M=16 N=64 K=64 =================
        {
            float4 f0 = *(const float4*)(x + xb + q4 * 8);
            float4 f1 = *(const float4*)(x + xb + q4 * 8 + 4);
            float4 f2 = *(const float4*)(x + xb + 32 + q4 * 8);
            float4 f3 = *(const float4*)(x + xb + 32 + q4 * 8 + 4);
            float v0[8] = {f0.x, f0.y, f0.z, f0.w, f1.x, f1.y, f1.z, f1.w};
            float v1[8] = {f2.x, f2.y, f2.z, f2.w, f3.x, f3.y, f3.z, f3.w};
            short8 a0 = pack8(v0), a1 = pack8(v1);
#pragma unroll
            for (int nt = 0; nt < 4; ++nt) {
                short8 b0 = *(const short8*)(sm + WT0_OFF + (nt * 16 + r) * 72 + q4 * 8);
                short8 b1 = *(const short8*)(sm + WT0_OFF + (nt * 16 + r) * 72 + 32 + q4 * 8);
                floatx4 acc = {0.f, 0.f, 0.f, 0.f};
                acc = __builtin_amdgcn_mfma_f32_16x16x32_bf16(a0, b0, acc, 0, 0, 0);
                acc = __builtin_amdgcn_mfma_f32_16x16x32_bf16(a1, b1, acc, 0, 0, 0);
#pragma unroll
                for (int rr = 0; rr < 4; ++rr)
                    if (vst[rr]) out[(size_t)nr[rr] * 240 + nt * 16 + r] = acc[rr];
            }
        }

        // ================= irrep1: per d: M=16 N=32 K=32 =================
        {
            short8 b0 = *(const short8*)(sm + WT1_OFF + r * 40 + q4 * 8);
            short8 b1 = *(const short8*)(sm + WT1_OFF + (16 + r) * 40 + q4 * 8);
#pragma unroll
            for (int d = 0; d < 3; ++d) {
                float xv[8];
#pragma unroll
                for (int j = 0; j < 8; ++j)
                    xv[j] = x[xb + 64 + (size_t)(q4 * 8 + j) * 3 + d];
                short8 a = pack8(xv);
                floatx4 acc = {0.f, 0.f, 0.f, 0.f};
                acc = __builtin_amdgcn_mfma_f32_16x16x32_bf16(a, b0, acc, 0, 0, 0);
#pragma unroll
                for (int rr = 0; rr < 4; ++rr)
                    if (vst[rr]) out[(size_t)nr[rr] * 240 + 64 + r * 3 + d] = acc[rr];
                floatx4 acc2 = {0.f, 0.f, 0.f, 0.f};
                acc2 = __builtin_amdgcn_mfma_f32_16x16x32_bf16(a, b1, acc2, 0, 0, 0);
#pragma unroll
                for (int rr = 0; rr < 4; ++rr)
                    if (vst[rr]) out[(size_t)nr[rr] * 240 + 64 + (16 + r) * 3 + d] = acc2[rr];
            }
        }

        // ================= irrep2: per d: M=16 N=16 K=16 (K-pad 32) =================
        {
            short8 b = *(const short8*)(sm + WT2_OFF + r * 40 + q4 * 8);
#pragma unroll
            for (int d = 0; d < 5; ++d) {
                short8 a = {0, 0, 0, 0, 0, 0, 0, 0};
                if (q4 < 2) {
                    float xv[8];
#pragma unroll
                    for (int j = 0; j < 8; ++j)
                        xv[j] = x[xb + 160 + (size_t)(q4 * 8 + j) * 5 + d];
                    a = pack8(xv);
                }
                floatx4 acc = {0.f, 0.f, 0.f, 0.f};
                acc = __builtin_amdgcn_mfma_f32_16x16x32_bf16(a, b, acc, 0, 0, 0);
#pragma unroll
                for (int rr = 0; rr < 4; ++rr)
                    if (vst[rr]) out[(size_t)nr[rr] * 240 + 160 + r * 5 + d] = acc[rr];
            }
        }
    }
}

extern "C" void kernel_launch(void* const* d_in, const int* in_sizes, int n_in,
                              void* d_out, int out_size, void* d_ws, size_t ws_size,
                              hipStream_t stream) {
    const float* x  = (const float*)d_in[0];
    const float* W0 = (const float*)d_in[1];
    const float* W1 = (const float*)d_in[2];
    const float* W2 = (const float*)d_in[3];
    const int*   idx = (const int*)d_in[4];
    float* out = (float*)d_out;
    const int n = in_sizes[4];          // 65536 nodes
    int* ws = (int*)d_ws;

    hist_kernel   <<<NB, 256, 0, stream>>>(idx, ws, n);
    scan_kernel   <<<1, 256, 0, stream>>>(ws, n);
    scatter_kernel<<<NB, 256, 0, stream>>>(idx, ws, n);
    main_kernel   <<<dim3(BPT, NTYPES), 256, 0, stream>>>(x, W0, W1, W2, ws, out);
}